// Round 1
// baseline (131.286 us; speedup 1.0000x reference)
//
#include <hip/hip_runtime.h>
#include <cstddef>

#define NT 10            // NUM_TOKENS
#define TD 96            // TOKEN_DIM == REF_DIM
#define NH 4             // NUM_HEADS
#define NPOS (32 * 2048) // B*T positions
#define TPB 256

__device__ __forceinline__ float fast_tanh(float x) {
    // tanh(x) = 1 - 2/(exp(2x)+1); exact limits at +/-inf, ~1e-6 rel error
    float e = __expf(2.0f * x);
    return 1.0f - 2.0f * __builtin_amdgcn_rcpf(e + 1.0f);
}

__global__ __launch_bounds__(TPB) void gst_fused(
    const float* __restrict__ ref_emb,
    const float* __restrict__ tokens,
    const float* __restrict__ Wq,
    const float* __restrict__ Wk,
    const float* __restrict__ Wv,
    float* __restrict__ out)
{
    // k = tanh(tokens @ Wk^T), stored transposed: kT[d][n] (pad 12 for float4 align)
    __shared__ float kT[TD][12];

    for (int idx = threadIdx.x; idx < NT * TD; idx += TPB) {
        int n = idx / TD;
        int d = idx - n * TD;
        const float4* tr = (const float4*)(tokens + n * TD);
        const float4* wr = (const float4*)(Wk + d * TD);
        float acc = 0.0f;
        #pragma unroll
        for (int j = 0; j < TD / 4; ++j) {
            float4 a = tr[j];
            float4 b = wr[j];
            acc = fmaf(a.x, b.x, acc);
            acc = fmaf(a.y, b.y, acc);
            acc = fmaf(a.z, b.z, acc);
            acc = fmaf(a.w, b.w, acc);
        }
        kT[d][n] = fast_tanh(acc);
    }
    __syncthreads();

    const int pos = blockIdx.x * TPB + threadIdx.x;

    // load this position's ref_emb row into registers (24 x float4)
    const float4* xr = (const float4*)(ref_emb + (size_t)pos * TD);
    float4 x[TD / 4];
    #pragma unroll
    for (int j = 0; j < TD / 4; ++j) x[j] = xr[j];

    float logits[NT][NH];
    #pragma unroll
    for (int n = 0; n < NT; ++n)
        #pragma unroll
        for (int h = 0; h < NH; ++h) logits[n][h] = 0.0f;

    // fused: q_d = tanh(x . Wq[d]); logits[n][h] += tanh(q_d + k[n][d]) * Wv[h][d]
    #pragma unroll 4
    for (int d = 0; d < TD; ++d) {
        const float4* wr = (const float4*)(Wq + d * TD); // uniform -> s_load
        float acc = 0.0f;
        #pragma unroll
        for (int j = 0; j < TD / 4; ++j) {
            float4 w = wr[j];
            acc = fmaf(x[j].x, w.x, acc);
            acc = fmaf(x[j].y, w.y, acc);
            acc = fmaf(x[j].z, w.z, acc);
            acc = fmaf(x[j].w, w.w, acc);
        }
        float q = fast_tanh(acc);

        float wv[NH];
        #pragma unroll
        for (int h = 0; h < NH; ++h) wv[h] = Wv[h * TD + d]; // uniform -> s_load

        #pragma unroll
        for (int n = 0; n < NT; ++n) {
            float s = fast_tanh(q + kT[d][n]); // LDS broadcast read
            #pragma unroll
            for (int h = 0; h < NH; ++h)
                logits[n][h] = fmaf(s, wv[h], logits[n][h]);
        }
    }

    // softmax over n (per head), then wn[n] = mean_h attn[n][h]
    float wn[NT];
    #pragma unroll
    for (int n = 0; n < NT; ++n) wn[n] = 0.0f;

    #pragma unroll
    for (int h = 0; h < NH; ++h) {
        float m = logits[0][h];
        #pragma unroll
        for (int n = 1; n < NT; ++n) m = fmaxf(m, logits[n][h]);
        float e[NT];
        float ssum = 0.0f;
        #pragma unroll
        for (int n = 0; n < NT; ++n) {
            e[n] = __expf(logits[n][h] - m);
            ssum += e[n];
        }
        float inv = 0.25f * __builtin_amdgcn_rcpf(ssum);
        #pragma unroll
        for (int n = 0; n < NT; ++n) wn[n] = fmaf(e[n], inv, wn[n]);
    }

    // style[d] = sum_n wn[n] * tokens[n][d]
    float4* op = (float4*)(out + (size_t)pos * TD);
    #pragma unroll
    for (int j = 0; j < TD / 4; ++j) {
        float4 o = make_float4(0.f, 0.f, 0.f, 0.f);
        #pragma unroll
        for (int n = 0; n < NT; ++n) {
            const float4 t = ((const float4*)(tokens + n * TD))[j]; // uniform -> s_load
            o.x = fmaf(wn[n], t.x, o.x);
            o.y = fmaf(wn[n], t.y, o.y);
            o.z = fmaf(wn[n], t.z, o.z);
            o.w = fmaf(wn[n], t.w, o.w);
        }
        op[j] = o;
    }
}

extern "C" void kernel_launch(void* const* d_in, const int* in_sizes, int n_in,
                              void* d_out, int out_size, void* d_ws, size_t ws_size,
                              hipStream_t stream) {
    const float* ref_emb = (const float*)d_in[0];
    const float* tokens  = (const float*)d_in[1];
    const float* Wq      = (const float*)d_in[2];
    const float* Wk      = (const float*)d_in[3];
    const float* Wv      = (const float*)d_in[4];
    float* out = (float*)d_out;

    gst_fused<<<NPOS / TPB, TPB, 0, stream>>>(ref_emb, tokens, Wq, Wk, Wv, out);
}